// Round 1
// baseline (1573.458 us; speedup 1.0000x reference)
//
#include <hip/hip_runtime.h>
#include <math.h>

#define BB 8
#define TT 2048
#define CC 1024
#define HH 64
constexpr float SCALE = 0.03125f; // 1024^-0.5 (reference scales by n_embd, not head_size)

// ---------------- Kernel 1: qkv projection ----------------
// k/q/v[b,t,h] = sum_c x[b,t,c] * W{k,q,v}[h,c]
// grid 512 blocks x 256 threads; 32 x-rows per block; K staged in LDS tiles of 256.
__global__ __launch_bounds__(256) void proj_kernel(
    const float* __restrict__ x, const float* __restrict__ Wk,
    const float* __restrict__ Wq, const float* __restrict__ Wv,
    float* __restrict__ kout, float* __restrict__ qout, float* __restrict__ vout)
{
    __shared__ float xt[32][260]; // stride 260: rows land on banks 4r%32 -> conflict-free
    const int tid = threadIdx.x;
    const int row0 = blockIdx.x * 32;
    const int r = tid >> 3;   // 0..31 x-row within tile
    const int g = tid & 7;    // 0..7

    // 24 output columns per thread: col = g + 8*(j&7); j/8 selects matrix (k,q,v)
    const float* wp[24];
#pragma unroll
    for (int j = 0; j < 24; ++j) {
        const float* W = (j < 8) ? Wk : (j < 16) ? Wq : Wv;
        wp[j] = W + (size_t)(g + 8 * (j & 7)) * CC;
    }

    float acc[24];
#pragma unroll
    for (int j = 0; j < 24; ++j) acc[j] = 0.f;

    for (int k0 = 0; k0 < CC; k0 += 256) {
        __syncthreads(); // previous tile's reads done before restage
#pragma unroll
        for (int it = 0; it < 8; ++it) {
            int idx = tid + 256 * it;   // float4 id 0..2047
            int rr = idx >> 6;          // 0..31
            int c4 = idx & 63;          // 0..63
            *reinterpret_cast<float4*>(&xt[rr][c4 * 4]) =
                *reinterpret_cast<const float4*>(&x[(size_t)(row0 + rr) * CC + k0 + c4 * 4]);
        }
        __syncthreads();
        for (int kk = 0; kk < 256; kk += 4) {
            float4 xv = *reinterpret_cast<const float4*>(&xt[r][kk]);
#pragma unroll
            for (int j = 0; j < 24; ++j) {
                float4 wv = *reinterpret_cast<const float4*>(&wp[j][k0 + kk]);
                acc[j] += xv.x * wv.x + xv.y * wv.y + xv.z * wv.z + xv.w * wv.w;
            }
        }
    }

    const size_t base = (size_t)(row0 + r) * HH;
#pragma unroll
    for (int j = 0; j < 24; ++j) {
        int c = g + 8 * (j & 7);
        float* o = (j < 8) ? kout : (j < 16) ? qout : vout;
        o[base + c] = acc[j];
    }
}

// ---------------- Kernel 2: causal flash attention ----------------
// grid 256 blocks (b * 32 qtiles of 64 rows) x 256 threads.
__global__ __launch_bounds__(256) void attn_kernel(
    const float* __restrict__ q, const float* __restrict__ k,
    const float* __restrict__ v, float* __restrict__ out)
{
    __shared__ float qt_[64][68];
    __shared__ float kt_[64][68];
    __shared__ float vt_[64][68];
    __shared__ float st_[64][68];
    __shared__ float red_[64][8]; // [row][0..3] max partials, [4..7] sum partials

    const int tid = threadIdx.x;
    const int b  = blockIdx.x >> 5;
    const int qt = blockIdx.x & 31;
    const float* qb = q + ((size_t)b * TT + qt * 64) * HH;
    const float* kb = k + (size_t)b * TT * HH;
    const float* vb = v + (size_t)b * TT * HH;

    // load q tile (64x64)
#pragma unroll
    for (int it = 0; it < 4; ++it) {
        int idx = tid + 256 * it;  // float4 id 0..1023
        int rr = idx >> 4, c4 = idx & 15;
        *reinterpret_cast<float4*>(&qt_[rr][c4 * 4]) =
            *reinterpret_cast<const float4*>(&qb[rr * HH + c4 * 4]);
    }

    const int tr = tid >> 4, tc = tid & 15;  // QK phase: 4x4 block at (4tr, 4tc)
    const int r = tid >> 2, sub = tid & 3;   // softmax/PV phase: row r, h-range sub*16..

    float m = -INFINITY, l = 0.f;
    float o[16];
#pragma unroll
    for (int i = 0; i < 16; ++i) o[i] = 0.f;

    for (int jt = 0; jt <= qt; ++jt) {
        __syncthreads(); // previous tile's st_/vt_ reads done
#pragma unroll
        for (int it = 0; it < 4; ++it) {
            int idx = tid + 256 * it;
            int rr = idx >> 4, c4 = idx & 15;
            *reinterpret_cast<float4*>(&kt_[rr][c4 * 4]) =
                *reinterpret_cast<const float4*>(&kb[(jt * 64 + rr) * HH + c4 * 4]);
            *reinterpret_cast<float4*>(&vt_[rr][c4 * 4]) =
                *reinterpret_cast<const float4*>(&vb[(jt * 64 + rr) * HH + c4 * 4]);
        }
        __syncthreads();

        // s = scale * q @ k^T, 4x4 register block
        float sacc[4][4] = {};
        for (int h = 0; h < 64; h += 4) {
            float4 qv[4], kv[4];
#pragma unroll
            for (int a = 0; a < 4; ++a) qv[a] = *reinterpret_cast<const float4*>(&qt_[4 * tr + a][h]);
#pragma unroll
            for (int c = 0; c < 4; ++c) kv[c] = *reinterpret_cast<const float4*>(&kt_[4 * tc + c][h]);
#pragma unroll
            for (int a = 0; a < 4; ++a)
#pragma unroll
                for (int c = 0; c < 4; ++c)
                    sacc[a][c] += qv[a].x * kv[c].x + qv[a].y * kv[c].y
                                + qv[a].z * kv[c].z + qv[a].w * kv[c].w;
        }
#pragma unroll
        for (int a = 0; a < 4; ++a)
#pragma unroll
            for (int c = 0; c < 4; ++c)
                st_[4 * tr + a][4 * tc + c] = sacc[a][c] * SCALE;
        __syncthreads();

        const bool diag = (jt == qt);
        // partial max over own 16 cols (masked)
        float pmax = -INFINITY;
#pragma unroll
        for (int jj = 0; jj < 16; ++jj) {
            int j = sub * 16 + jj;
            float sv = st_[r][j];
            if (diag && j > r) sv = -INFINITY;
            pmax = fmaxf(pmax, sv);
        }
        red_[r][sub] = pmax;
        __syncthreads();
        float mnew = fmaxf(fmaxf(red_[r][0], red_[r][1]), fmaxf(red_[r][2], red_[r][3]));
        mnew = fmaxf(m, mnew);

        // p = exp(s - mnew) for own 16 cols, write back, partial sum
        float psum = 0.f;
#pragma unroll
        for (int jj = 0; jj < 16; ++jj) {
            int j = sub * 16 + jj;
            float sv = st_[r][j];
            float p = (diag && j > r) ? 0.f : __expf(sv - mnew);
            st_[r][j] = p;
            psum += p;
        }
        red_[r][4 + sub] = psum;
        __syncthreads();
        float ptot = red_[r][4] + red_[r][5] + red_[r][6] + red_[r][7];

        float alpha = __expf(m - mnew); // m=-inf on first tile -> alpha=0
        l = l * alpha + ptot;
        m = mnew;
#pragma unroll
        for (int i = 0; i < 16; ++i) o[i] *= alpha;

        // o[h0..h0+15] += sum_j p[j] * v[j][h]
        const int h0 = sub * 16;
        for (int j = 0; j < 64; ++j) {
            float pj = st_[r][j];
#pragma unroll
            for (int c4 = 0; c4 < 4; ++c4) {
                float4 vv = *reinterpret_cast<const float4*>(&vt_[j][h0 + c4 * 4]);
                o[c4 * 4 + 0] += pj * vv.x;
                o[c4 * 4 + 1] += pj * vv.y;
                o[c4 * 4 + 2] += pj * vv.z;
                o[c4 * 4 + 3] += pj * vv.w;
            }
        }
    }

    float inv = 1.f / l;
    float* ob = out + ((size_t)b * TT + qt * 64 + r) * HH + sub * 16;
#pragma unroll
    for (int c4 = 0; c4 < 4; ++c4) {
        float4 ov = { o[c4 * 4] * inv, o[c4 * 4 + 1] * inv,
                      o[c4 * 4 + 2] * inv, o[c4 * 4 + 3] * inv };
        *reinterpret_cast<float4*>(&ob[c4 * 4]) = ov;
    }
}

extern "C" void kernel_launch(void* const* d_in, const int* in_sizes, int n_in,
                              void* d_out, int out_size, void* d_ws, size_t ws_size,
                              hipStream_t stream) {
    const float* x  = (const float*)d_in[0];
    const float* Wk = (const float*)d_in[1];
    const float* Wq = (const float*)d_in[2];
    const float* Wv = (const float*)d_in[3];
    float* outp = (float*)d_out;

    const size_t n = (size_t)BB * TT * HH; // 1,048,576
    float* kbuf = (float*)d_ws;
    float* qbuf = kbuf + n;
    float* vbuf = qbuf + n;

    proj_kernel<<<512, 256, 0, stream>>>(x, Wk, Wq, Wv, kbuf, qbuf, vbuf);
    attn_kernel<<<256, 256, 0, stream>>>(qbuf, kbuf, vbuf, outp);
}

// Round 5
// 285.333 us; speedup vs baseline: 5.5145x; 5.5145x over previous
//
#include <hip/hip_runtime.h>
#include <math.h>

#define BB 8
#define TT 2048
#define CC 1024
#define HH 64
constexpr float SCALE = 0.03125f; // 1024^-0.5 (reference scales by n_embd, not head_size)

typedef __attribute__((ext_vector_type(8))) short bf16x8;
typedef __attribute__((ext_vector_type(4))) short s16x4;
typedef __attribute__((ext_vector_type(4))) float f32x4;

static __device__ __forceinline__ short f2bf(float f) {
    union { float f; unsigned u; } un; un.f = f;
    unsigned r = un.u + 0x7FFFu + ((un.u >> 16) & 1u); // RNE
    return (short)(r >> 16);
}

// ---------------- Kernel 1: qkv projection, bf16 MFMA ----------------
// out[t][h] = sum_c x[t][c] * W[h][c]   (C = A . B^T, both row-major, K contiguous)
// grid (256, 3) x 256 thr. BM=64 rows, BN=64 cols (=H), BK=64.
__global__ __launch_bounds__(256) void proj_mfma(
    const float* __restrict__ x,
    const float* __restrict__ Wk, const float* __restrict__ Wq, const float* __restrict__ Wv,
    float* __restrict__ ko, float* __restrict__ qo, float* __restrict__ vo)
{
    const float* W; float* out;
    if (blockIdx.y == 0)      { W = Wk; out = ko; }
    else if (blockIdx.y == 1) { W = Wq; out = qo; }
    else                      { W = Wv; out = vo; }

    __shared__ short At[64][68]; // [row][k], +4 pad -> 136B stride, conflict-free
    __shared__ short Bt[64][68]; // [hcol][k]

    const int tid  = threadIdx.x;
    const int row0 = blockIdx.x * 64;
    const int wave = tid >> 6, lane = tid & 63;
    const int wm = wave >> 1, wn = wave & 1; // 32x32 quadrant
    const int lr = lane & 15, lg = lane >> 4;

    f32x4 acc[2][2] = {};

    for (int k0 = 0; k0 < CC; k0 += 64) {
        __syncthreads(); // previous tile's reads complete
        // stage A (x) and B (W): 64x64 fp32 -> bf16 each; 4 float4 per thread per tile
#pragma unroll
        for (int it = 0; it < 4; ++it) {
            int idx = tid + 256 * it;
            int rr = idx >> 4, c4 = (idx & 15) * 4;
            float4 xv = *reinterpret_cast<const float4*>(&x[(size_t)(row0 + rr) * CC + k0 + c4]);
            s16x4 hv = { f2bf(xv.x), f2bf(xv.y), f2bf(xv.z), f2bf(xv.w) };
            *reinterpret_cast<s16x4*>(&At[rr][c4]) = hv;
            float4 wv = *reinterpret_cast<const float4*>(&W[(size_t)rr * CC + k0 + c4]);
            s16x4 hw = { f2bf(wv.x), f2bf(wv.y), f2bf(wv.z), f2bf(wv.w) };
            *reinterpret_cast<s16x4*>(&Bt[rr][c4]) = hw;
        }
        __syncthreads();

#pragma unroll
        for (int kk = 0; kk < 64; kk += 32) {
            // operand element i: k = kk + 4*lg + (i&3) + 16*(i>>2); row/col = lr
            bf16x8 aF[2], bF[2];
#pragma unroll
            for (int m = 0; m < 2; ++m) {
                int row = wm * 32 + m * 16 + lr;
                s16x4 lo = *reinterpret_cast<const s16x4*>(&At[row][kk + 4 * lg]);
                s16x4 hi = *reinterpret_cast<const s16x4*>(&At[row][kk + 16 + 4 * lg]);
                aF[m] = __builtin_shufflevector(lo, hi, 0, 1, 2, 3, 4, 5, 6, 7);
            }
#pragma unroll
            for (int n = 0; n < 2; ++n) {
                int col = wn * 32 + n * 16 + lr;
                s16x4 lo = *reinterpret_cast<const s16x4*>(&Bt[col][kk + 4 * lg]);
                s16x4 hi = *reinterpret_cast<const s16x4*>(&Bt[col][kk + 16 + 4 * lg]);
                bF[n] = __builtin_shufflevector(lo, hi, 0, 1, 2, 3, 4, 5, 6, 7);
            }
#pragma unroll
            for (int m = 0; m < 2; ++m)
#pragma unroll
                for (int n = 0; n < 2; ++n)
                    acc[m][n] = __builtin_amdgcn_mfma_f32_16x16x32_bf16(aF[m], bF[n], acc[m][n], 0, 0, 0);
        }
    }

    // C/D layout: col = lane&15, row = 4*(lane>>4) + reg   [m89-verified]
#pragma unroll
    for (int m = 0; m < 2; ++m)
#pragma unroll
        for (int n = 0; n < 2; ++n)
#pragma unroll
            for (int j = 0; j < 4; ++j) {
                int grow = row0 + wm * 32 + m * 16 + lg * 4 + j;
                int gcol = wn * 32 + n * 16 + lr;
                out[(size_t)grow * HH + gcol] = acc[m][n][j];
            }
}

// ---------------- Kernel 2: causal flash attention (unchanged fp32) ----------------
__global__ __launch_bounds__(256) void attn_kernel(
    const float* __restrict__ q, const float* __restrict__ k,
    const float* __restrict__ v, float* __restrict__ out)
{
    __shared__ float qt_[64][68];
    __shared__ float kt_[64][68];
    __shared__ float vt_[64][68];
    __shared__ float st_[64][68];
    __shared__ float red_[64][8];

    const int tid = threadIdx.x;
    const int b  = blockIdx.x >> 5;
    const int qt = blockIdx.x & 31;
    const float* qb = q + ((size_t)b * TT + qt * 64) * HH;
    const float* kb = k + (size_t)b * TT * HH;
    const float* vb = v + (size_t)b * TT * HH;

#pragma unroll
    for (int it = 0; it < 4; ++it) {
        int idx = tid + 256 * it;
        int rr = idx >> 4, c4 = idx & 15;
        *reinterpret_cast<float4*>(&qt_[rr][c4 * 4]) =
            *reinterpret_cast<const float4*>(&qb[rr * HH + c4 * 4]);
    }

    const int tr = tid >> 4, tc = tid & 15;
    const int r = tid >> 2, sub = tid & 3;

    float m = -INFINITY, l = 0.f;
    float o[16];
#pragma unroll
    for (int i = 0; i < 16; ++i) o[i] = 0.f;

    for (int jt = 0; jt <= qt; ++jt) {
        __syncthreads();
#pragma unroll
        for (int it = 0; it < 4; ++it) {
            int idx = tid + 256 * it;
            int rr = idx >> 4, c4 = idx & 15;
            *reinterpret_cast<float4*>(&kt_[rr][c4 * 4]) =
                *reinterpret_cast<const float4*>(&kb[(jt * 64 + rr) * HH + c4 * 4]);
            *reinterpret_cast<float4*>(&vt_[rr][c4 * 4]) =
                *reinterpret_cast<const float4*>(&vb[(jt * 64 + rr) * HH + c4 * 4]);
        }
        __syncthreads();

        float sacc[4][4] = {};
        for (int h = 0; h < 64; h += 4) {
            float4 qv[4], kv[4];
#pragma unroll
            for (int a = 0; a < 4; ++a) qv[a] = *reinterpret_cast<const float4*>(&qt_[4 * tr + a][h]);
#pragma unroll
            for (int c = 0; c < 4; ++c) kv[c] = *reinterpret_cast<const float4*>(&kt_[4 * tc + c][h]);
#pragma unroll
            for (int a = 0; a < 4; ++a)
#pragma unroll
                for (int c = 0; c < 4; ++c)
                    sacc[a][c] += qv[a].x * kv[c].x + qv[a].y * kv[c].y
                                + qv[a].z * kv[c].z + qv[a].w * kv[c].w;
        }
#pragma unroll
        for (int a = 0; a < 4; ++a)
#pragma unroll
            for (int c = 0; c < 4; ++c)
                st_[4 * tr + a][4 * tc + c] = sacc[a][c] * SCALE;
        __syncthreads();

        const bool diag = (jt == qt);
        float pmax = -INFINITY;
#pragma unroll
        for (int jj = 0; jj < 16; ++jj) {
            int j = sub * 16 + jj;
            float sv = st_[r][j];
            if (diag && j > r) sv = -INFINITY;
            pmax = fmaxf(pmax, sv);
        }
        red_[r][sub] = pmax;
        __syncthreads();
        float mnew = fmaxf(fmaxf(red_[r][0], red_[r][1]), fmaxf(red_[r][2], red_[r][3]));
        mnew = fmaxf(m, mnew);

        float psum = 0.f;
#pragma unroll
        for (int jj = 0; jj < 16; ++jj) {
            int j = sub * 16 + jj;
            float sv = st_[r][j];
            float p = (diag && j > r) ? 0.f : __expf(sv - mnew);
            st_[r][j] = p;
            psum += p;
        }
        red_[r][4 + sub] = psum;
        __syncthreads();
        float ptot = red_[r][4] + red_[r][5] + red_[r][6] + red_[r][7];

        float alpha = __expf(m - mnew);
        l = l * alpha + ptot;
        m = mnew;
#pragma unroll
        for (int i = 0; i < 16; ++i) o[i] *= alpha;

        const int h0 = sub * 16;
        for (int j = 0; j < 64; ++j) {
            float pj = st_[r][j];
#pragma unroll
            for (int c4 = 0; c4 < 4; ++c4) {
                float4 vv = *reinterpret_cast<const float4*>(&vt_[j][h0 + c4 * 4]);
                o[c4 * 4 + 0] += pj * vv.x;
                o[c4 * 4 + 1] += pj * vv.y;
                o[c4 * 4 + 2] += pj * vv.z;
                o[c4 * 4 + 3] += pj * vv.w;
            }
        }
    }

    float inv = 1.f / l;
    float* ob = out + ((size_t)b * TT + qt * 64 + r) * HH + sub * 16;
#pragma unroll
    for (int c4 = 0; c4 < 4; ++c4) {
        float4 ov = { o[c4 * 4] * inv, o[c4 * 4 + 1] * inv,
                      o[c4 * 4 + 2] * inv, o[c4 * 4 + 3] * inv };
        *reinterpret_cast<float4*>(&ob[c4 * 4]) = ov;
    }
}

extern "C" void kernel_launch(void* const* d_in, const int* in_sizes, int n_in,
                              void* d_out, int out_size, void* d_ws, size_t ws_size,
                              hipStream_t stream) {
    const float* x  = (const float*)d_in[0];
    const float* Wk = (const float*)d_in[1];
    const float* Wq = (const float*)d_in[2];
    const float* Wv = (const float*)d_in[3];
    float* outp = (float*)d_out;

    const size_t n = (size_t)BB * TT * HH;
    float* kbuf = (float*)d_ws;
    float* qbuf = kbuf + n;
    float* vbuf = qbuf + n;

    dim3 pgrid(256, 3);
    proj_mfma<<<pgrid, 256, 0, stream>>>(x, Wk, Wq, Wv, kbuf, qbuf, vbuf);
    attn_kernel<<<256, 256, 0, stream>>>(qbuf, kbuf, vbuf, outp);
}

// Round 6
// 123.080 us; speedup vs baseline: 12.7840x; 2.3183x over previous
//
#include <hip/hip_runtime.h>
#include <math.h>

#define BB 8
#define TT 2048
#define CC 1024
#define HH 64
constexpr float SCALE = 0.03125f; // 1024^-0.5 (reference scales by n_embd)

typedef __attribute__((ext_vector_type(8))) short bf16x8;
typedef __attribute__((ext_vector_type(8))) short s16x8;
typedef __attribute__((ext_vector_type(4))) short s16x4;
typedef __attribute__((ext_vector_type(4))) float f32x4;

static __device__ __forceinline__ short f2bf(float f) {
    union { float f; unsigned u; } un; un.f = f;
    unsigned r = un.u + 0x7FFFu + ((un.u >> 16) & 1u); // RNE
    return (short)(r >> 16);
}

// ---------------- Kernel 1: qkv projection, bf16 MFMA, bf16 outputs ----------------
__global__ __launch_bounds__(256) void proj_mfma(
    const float* __restrict__ x,
    const float* __restrict__ Wk, const float* __restrict__ Wq, const float* __restrict__ Wv,
    short* __restrict__ ko, short* __restrict__ qo, short* __restrict__ vo)
{
    const float* W; short* out;
    if (blockIdx.y == 0)      { W = Wk; out = ko; }
    else if (blockIdx.y == 1) { W = Wq; out = qo; }
    else                      { W = Wv; out = vo; }

    __shared__ short At[64][68];
    __shared__ short Bt[64][68];

    const int tid  = threadIdx.x;
    const int row0 = blockIdx.x * 64;
    const int wave = tid >> 6, lane = tid & 63;
    const int wm = wave >> 1, wn = wave & 1;
    const int lr = lane & 15, lg = lane >> 4;

    f32x4 acc[2][2] = {};

    for (int k0 = 0; k0 < CC; k0 += 64) {
        __syncthreads();
#pragma unroll
        for (int it = 0; it < 4; ++it) {
            int idx = tid + 256 * it;
            int rr = idx >> 4, c4 = (idx & 15) * 4;
            float4 xv = *reinterpret_cast<const float4*>(&x[(size_t)(row0 + rr) * CC + k0 + c4]);
            s16x4 hv = { f2bf(xv.x), f2bf(xv.y), f2bf(xv.z), f2bf(xv.w) };
            *reinterpret_cast<s16x4*>(&At[rr][c4]) = hv;
            float4 wv = *reinterpret_cast<const float4*>(&W[(size_t)rr * CC + k0 + c4]);
            s16x4 hw = { f2bf(wv.x), f2bf(wv.y), f2bf(wv.z), f2bf(wv.w) };
            *reinterpret_cast<s16x4*>(&Bt[rr][c4]) = hw;
        }
        __syncthreads();

#pragma unroll
        for (int kk = 0; kk < 64; kk += 32) {
            bf16x8 aF[2], bF[2];
#pragma unroll
            for (int m = 0; m < 2; ++m) {
                int row = wm * 32 + m * 16 + lr;
                s16x4 lo = *reinterpret_cast<const s16x4*>(&At[row][kk + 4 * lg]);
                s16x4 hi = *reinterpret_cast<const s16x4*>(&At[row][kk + 16 + 4 * lg]);
                aF[m] = __builtin_shufflevector(lo, hi, 0, 1, 2, 3, 4, 5, 6, 7);
            }
#pragma unroll
            for (int n = 0; n < 2; ++n) {
                int col = wn * 32 + n * 16 + lr;
                s16x4 lo = *reinterpret_cast<const s16x4*>(&Bt[col][kk + 4 * lg]);
                s16x4 hi = *reinterpret_cast<const s16x4*>(&Bt[col][kk + 16 + 4 * lg]);
                bF[n] = __builtin_shufflevector(lo, hi, 0, 1, 2, 3, 4, 5, 6, 7);
            }
#pragma unroll
            for (int m = 0; m < 2; ++m)
#pragma unroll
                for (int n = 0; n < 2; ++n)
                    acc[m][n] = __builtin_amdgcn_mfma_f32_16x16x32_bf16(aF[m], bF[n], acc[m][n], 0, 0, 0);
        }
    }

#pragma unroll
    for (int m = 0; m < 2; ++m)
#pragma unroll
        for (int n = 0; n < 2; ++n)
#pragma unroll
            for (int j = 0; j < 4; ++j) {
                int grow = row0 + wm * 32 + m * 16 + lg * 4 + j;
                int gcol = wn * 32 + n * 16 + lr;
                out[(size_t)grow * HH + gcol] = f2bf(acc[m][n][j]);
            }
}

// ---------------- Kernel 2: causal flash attention, bf16 MFMA ----------------
// grid 256 blocks (b * 32 q-tiles of 64 rows) x 256 thr; wave w owns rows [w*16, w*16+16)
__global__ __launch_bounds__(256) void attn_mfma(
    const short* __restrict__ q, const short* __restrict__ k,
    const short* __restrict__ v, float* __restrict__ out)
{
    __shared__ short Qt[64][72];        // [row][h]
    __shared__ short Kt[64][72];        // [kv][h]
    __shared__ short Vt[64][70];        // [h][kv]  (transposed for PV B-frags)
    __shared__ short pst[4][16][72];    // wave-private P round-trip [row][kv]

    const int tid = threadIdx.x;
    const int b  = blockIdx.x >> 5;
    const int jq = blockIdx.x & 31;
    const int qb0 = jq * 64;
    const int wave = tid >> 6, lane = tid & 63;
    const int lr = lane & 15, lg = lane >> 4;

    const short* qb = q + ((size_t)b * TT + qb0) * HH;
    const short* kb = k + (size_t)b * TT * HH;
    const short* vb = v + (size_t)b * TT * HH;

    // stage Q tile once
#pragma unroll
    for (int it = 0; it < 2; ++it) {
        int idx = tid + 256 * it;
        int row = idx >> 3, c8 = (idx & 7) * 8;
        *reinterpret_cast<s16x8*>(&Qt[row][c8]) =
            *reinterpret_cast<const s16x8*>(&qb[row * HH + c8]);
    }
    __syncthreads();

    bf16x8 aQ[2];
    const int wrow = wave * 16 + lr;
#pragma unroll
    for (int k2 = 0; k2 < 2; ++k2) {
        s16x4 lo = *reinterpret_cast<const s16x4*>(&Qt[wrow][k2 * 32 + 4 * lg]);
        s16x4 hi = *reinterpret_cast<const s16x4*>(&Qt[wrow][k2 * 32 + 16 + 4 * lg]);
        aQ[k2] = __builtin_shufflevector(lo, hi, 0, 1, 2, 3, 4, 5, 6, 7);
    }

    f32x4 o[4] = {};
    float m_run[4], l_run[4];
#pragma unroll
    for (int j = 0; j < 4; ++j) { m_run[j] = -INFINITY; l_run[j] = 0.f; }

    for (int jt = 0; jt <= jq; ++jt) {
        __syncthreads(); // previous tile's Kt/Vt reads complete
#pragma unroll
        for (int it = 0; it < 2; ++it) {
            int idx = tid + 256 * it;
            int row = idx >> 3, c8 = (idx & 7) * 8;
            *reinterpret_cast<s16x8*>(&Kt[row][c8]) =
                *reinterpret_cast<const s16x8*>(&kb[(size_t)(jt * 64 + row) * HH + c8]);
            s16x8 vv = *reinterpret_cast<const s16x8*>(&vb[(size_t)(jt * 64 + row) * HH + c8]);
#pragma unroll
            for (int u = 0; u < 8; ++u) Vt[c8 + u][row] = vv[u];
        }
        __syncthreads();

        // ---- S = Q K^T (16 rows x 64 kv per wave) ----
        f32x4 s[4];
#pragma unroll
        for (int n = 0; n < 4; ++n) s[n] = (f32x4){0.f, 0.f, 0.f, 0.f};
#pragma unroll
        for (int k2 = 0; k2 < 2; ++k2) {
#pragma unroll
            for (int n = 0; n < 4; ++n) {
                s16x4 lo = *reinterpret_cast<const s16x4*>(&Kt[n * 16 + lr][k2 * 32 + 4 * lg]);
                s16x4 hi = *reinterpret_cast<const s16x4*>(&Kt[n * 16 + lr][k2 * 32 + 16 + 4 * lg]);
                bf16x8 bk = __builtin_shufflevector(lo, hi, 0, 1, 2, 3, 4, 5, 6, 7);
                s[n] = __builtin_amdgcn_mfma_f32_16x16x32_bf16(aQ[k2], bk, s[n], 0, 0, 0);
            }
        }

        // ---- causal mask (diag tile only) ----
        if (jt == jq) {
#pragma unroll
            for (int n = 0; n < 4; ++n)
#pragma unroll
                for (int j = 0; j < 4; ++j)
                    if (n * 16 + lr > wave * 16 + 4 * lg + j) s[n][j] = -3.0e38f;
        }

        // ---- online softmax (in registers; rows 4lg+j, cols across lr) ----
        float tm[4], mnew[4], alpha[4], psum[4];
#pragma unroll
        for (int j = 0; j < 4; ++j)
            tm[j] = fmaxf(fmaxf(s[0][j], s[1][j]), fmaxf(s[2][j], s[3][j]));
#pragma unroll
        for (int off = 1; off <= 8; off <<= 1)
#pragma unroll
            for (int j = 0; j < 4; ++j)
                tm[j] = fmaxf(tm[j], __shfl_xor(tm[j], off));
#pragma unroll
        for (int j = 0; j < 4; ++j) {
            mnew[j]  = fmaxf(m_run[j], tm[j] * SCALE);
            alpha[j] = __expf(m_run[j] - mnew[j]); // -inf first tile -> 0
            m_run[j] = mnew[j];
            psum[j]  = 0.f;
        }
#pragma unroll
        for (int n = 0; n < 4; ++n)
#pragma unroll
            for (int j = 0; j < 4; ++j) {
                float p = __expf(fmaf(s[n][j], SCALE, -mnew[j])); // masked -> exp(-huge)=0
                psum[j] += p;
                pst[wave][4 * lg + j][n * 16 + lr] = f2bf(p);
            }
#pragma unroll
        for (int off = 1; off <= 8; off <<= 1)
#pragma unroll
            for (int j = 0; j < 4; ++j)
                psum[j] += __shfl_xor(psum[j], off);
#pragma unroll
        for (int j = 0; j < 4; ++j)
            l_run[j] = l_run[j] * alpha[j] + psum[j];
#pragma unroll
        for (int n = 0; n < 4; ++n)
#pragma unroll
            for (int j = 0; j < 4; ++j)
                o[n][j] *= alpha[j];

        // ---- PV: O += P V (wave-private P round-trip; no block barrier) ----
        asm volatile("s_waitcnt lgkmcnt(0)" ::: "memory");
        bf16x8 aP[2];
#pragma unroll
        for (int k2 = 0; k2 < 2; ++k2) {
            s16x4 lo = *reinterpret_cast<const s16x4*>(&pst[wave][lr][k2 * 32 + 4 * lg]);
            s16x4 hi = *reinterpret_cast<const s16x4*>(&pst[wave][lr][k2 * 32 + 16 + 4 * lg]);
            aP[k2] = __builtin_shufflevector(lo, hi, 0, 1, 2, 3, 4, 5, 6, 7);
        }
#pragma unroll
        for (int k2 = 0; k2 < 2; ++k2) {
            int kv0 = k2 * 32 + 4 * lg;
#pragma unroll
            for (int n = 0; n < 4; ++n) {
                union { int4 i; bf16x8 h; } cv;
                cv.i.x = *reinterpret_cast<const int*>(&Vt[n * 16 + lr][kv0]);
                cv.i.y = *reinterpret_cast<const int*>(&Vt[n * 16 + lr][kv0 + 2]);
                cv.i.z = *reinterpret_cast<const int*>(&Vt[n * 16 + lr][kv0 + 16]);
                cv.i.w = *reinterpret_cast<const int*>(&Vt[n * 16 + lr][kv0 + 18]);
                o[n] = __builtin_amdgcn_mfma_f32_16x16x32_bf16(aP[k2], cv.h, o[n], 0, 0, 0);
            }
        }
    }

    float inv[4];
#pragma unroll
    for (int j = 0; j < 4; ++j) inv[j] = 1.f / l_run[j];
    float* ob = out + ((size_t)b * TT + qb0) * HH;
#pragma unroll
    for (int n = 0; n < 4; ++n)
#pragma unroll
        for (int j = 0; j < 4; ++j)
            ob[(size_t)(wave * 16 + 4 * lg + j) * HH + n * 16 + lr] = o[n][j] * inv[j];
}

extern "C" void kernel_launch(void* const* d_in, const int* in_sizes, int n_in,
                              void* d_out, int out_size, void* d_ws, size_t ws_size,
                              hipStream_t stream) {
    const float* x  = (const float*)d_in[0];
    const float* Wk = (const float*)d_in[1];
    const float* Wq = (const float*)d_in[2];
    const float* Wv = (const float*)d_in[3];
    float* outp = (float*)d_out;

    const size_t n = (size_t)BB * TT * HH; // 1,048,576
    short* kbuf = (short*)d_ws;
    short* qbuf = kbuf + n;
    short* vbuf = qbuf + n;

    dim3 pgrid(256, 3);
    proj_mfma<<<pgrid, 256, 0, stream>>>(x, Wk, Wq, Wv, kbuf, qbuf, vbuf);
    attn_mfma<<<256, 256, 0, stream>>>(qbuf, kbuf, vbuf, outp);
}

// Round 7
// 110.266 us; speedup vs baseline: 14.2697x; 1.1162x over previous
//
#include <hip/hip_runtime.h>
#include <math.h>

#define BB 8
#define TT 2048
#define CC 1024
#define HH 64
constexpr float SCALE = 0.03125f;              // 1024^-0.5 (reference scales by n_embd)
constexpr float SC2   = 0.03125f * 1.4426950408889634f; // SCALE * log2(e)

typedef __attribute__((ext_vector_type(8))) short bf16x8;
typedef __attribute__((ext_vector_type(8))) short s16x8;
typedef __attribute__((ext_vector_type(4))) short s16x4;
typedef __attribute__((ext_vector_type(4))) float f32x4;

static __device__ __forceinline__ short f2bf(float f) {
    union { float f; unsigned u; } un; un.f = f;
    unsigned r = un.u + 0x7FFFu + ((un.u >> 16) & 1u); // RNE
    return (short)(r >> 16);
}
static __device__ __forceinline__ bf16x8 cat8(s16x4 lo, s16x4 hi) {
    return __builtin_shufflevector(lo, hi, 0, 1, 2, 3, 4, 5, 6, 7);
}

// ---------------- Kernel 1: fused qkv projection, bf16 MFMA ----------------
// Reads x once; computes k,q row-major [b][t][h] bf16 and v TRANSPOSED vT[b][h][t] bf16.
// grid 256 x 256 thr. BM=64 rows, BN=192 (3 matrices x 64), BK=64.
__global__ __launch_bounds__(256) void proj_fused(
    const float* __restrict__ x,
    const float* __restrict__ Wk, const float* __restrict__ Wq, const float* __restrict__ Wv,
    short* __restrict__ ko, short* __restrict__ qo, short* __restrict__ vT)
{
    __shared__ short At[64][68];
    __shared__ short Bt[192][68];

    const int tid  = threadIdx.x;
    const int row0 = blockIdx.x * 64;
    const int wave = tid >> 6, lane = tid & 63;
    const int wm = wave >> 1, wn = wave & 1;   // wm: 32-row half, wn: 96-col half
    const int lr = lane & 15, lg = lane >> 4;

    f32x4 acc[2][6] = {};

    for (int k0 = 0; k0 < CC; k0 += 64) {
        __syncthreads();
#pragma unroll
        for (int it = 0; it < 4; ++it) {               // A: 64x64
            int idx = tid + 256 * it;
            int rr = idx >> 4, c4 = (idx & 15) * 4;
            float4 xv = *reinterpret_cast<const float4*>(&x[(size_t)(row0 + rr) * CC + k0 + c4]);
            s16x4 hv = { f2bf(xv.x), f2bf(xv.y), f2bf(xv.z), f2bf(xv.w) };
            *reinterpret_cast<s16x4*>(&At[rr][c4]) = hv;
        }
#pragma unroll
        for (int it = 0; it < 12; ++it) {              // B: 192x64 (Wk|Wq|Wv)
            int idx = tid + 256 * it;
            int rr = idx >> 4, c4 = (idx & 15) * 4;
            const float* Wp = (rr < 64) ? Wk : (rr < 128) ? Wq : Wv;
            int wr = rr & 63;
            float4 wv = *reinterpret_cast<const float4*>(&Wp[(size_t)wr * CC + k0 + c4]);
            s16x4 hw = { f2bf(wv.x), f2bf(wv.y), f2bf(wv.z), f2bf(wv.w) };
            *reinterpret_cast<s16x4*>(&Bt[rr][c4]) = hw;
        }
        __syncthreads();

#pragma unroll
        for (int kk = 0; kk < 64; kk += 32) {
            bf16x8 aF[2], bF[6];
#pragma unroll
            for (int m = 0; m < 2; ++m) {
                int row = wm * 32 + m * 16 + lr;
                aF[m] = cat8(*reinterpret_cast<const s16x4*>(&At[row][kk + 4 * lg]),
                             *reinterpret_cast<const s16x4*>(&At[row][kk + 16 + 4 * lg]));
            }
#pragma unroll
            for (int n = 0; n < 6; ++n) {
                int brow = wn * 96 + n * 16 + lr;
                bF[n] = cat8(*reinterpret_cast<const s16x4*>(&Bt[brow][kk + 4 * lg]),
                             *reinterpret_cast<const s16x4*>(&Bt[brow][kk + 16 + 4 * lg]));
            }
#pragma unroll
            for (int m = 0; m < 2; ++m)
#pragma unroll
                for (int n = 0; n < 6; ++n)
                    acc[m][n] = __builtin_amdgcn_mfma_f32_16x16x32_bf16(aF[m], bF[n], acc[m][n], 0, 0, 0);
        }
    }

    // C-write. acc[m][n][j]: t-row = row0 + wm*32 + m*16 + 4*lg + j, col = wn*96 + n*16 + lr
    const int bb = row0 >> 11;       // batch (64 | 2048)
    const int t0 = row0 & 2047;
#pragma unroll
    for (int m = 0; m < 2; ++m)
#pragma unroll
        for (int n = 0; n < 6; ++n) {
            const int col0 = wn * 96 + n * 16;    // frag lies in one matrix (16 | 64)
            const int mat  = col0 >> 6;
            const int hcol = (col0 & 63) + lr;
            const int trow = wm * 32 + m * 16 + 4 * lg;
            if (mat == 2) {
                // vT[b][h][t]: 4 consecutive t -> one 8B store
                s16x4 pk = { f2bf(acc[m][n][0]), f2bf(acc[m][n][1]),
                             f2bf(acc[m][n][2]), f2bf(acc[m][n][3]) };
                *reinterpret_cast<s16x4*>(&vT[((size_t)bb * HH + hcol) * TT + t0 + trow]) = pk;
            } else {
                short* o = (mat == 0) ? ko : qo;
#pragma unroll
                for (int j = 0; j < 4; ++j)
                    o[(size_t)(row0 + trow + j) * HH + hcol] = f2bf(acc[m][n][j]);
            }
        }
}

// ---------------- Kernel 2: causal flash attention, 1 wave/block, register-resident ----------------
// grid 1024 blocks (jq*8 + b; %8 spreads batches across XCDs) x 64 thr.
// Wave owns 16 q-rows; K/V fragments loaded directly global->reg (L2-resident).
__global__ __launch_bounds__(64, 2) void attn_reg(
    const short* __restrict__ q, const short* __restrict__ k,
    const short* __restrict__ vT, float* __restrict__ out)
{
    __shared__ short pst[16][76];   // wave-private P round-trip; stride 76 -> conflict-free

    const int lane = threadIdx.x;
    const int blk = blockIdx.x;
    const int b  = blk & 7;
    const int jq = blk >> 3;        // 0..127, q-tile of 16 rows
    const int q0 = jq * 16;
    const int lr = lane & 15, lg = lane >> 4;

    const short* qb = q  + ((size_t)b * TT + q0) * HH;
    const short* kb = k  + (size_t)b * TT * HH;
    const short* vb = vT + (size_t)b * HH * TT;

    bf16x8 aQ[2];
#pragma unroll
    for (int k2 = 0; k2 < 2; ++k2)
        aQ[k2] = cat8(*reinterpret_cast<const s16x4*>(&qb[lr * HH + k2 * 32 + 4 * lg]),
                      *reinterpret_cast<const s16x4*>(&qb[lr * HH + k2 * 32 + 16 + 4 * lg]));

    f32x4 o[4] = {};
    float m2[4], l_run[4];
#pragma unroll
    for (int j = 0; j < 4; ++j) { m2[j] = -INFINITY; l_run[j] = 0.f; }

    const int ntiles = (jq >> 2) + 1;
    for (int jt = 0; jt < ntiles; ++jt) {
        const short* kt = kb + (size_t)jt * 64 * HH;
        const short* vt = vb + jt * 64;

        // issue all K and V loads up front (overlap with softmax below)
        s16x4 kf[8][2], vf[8][2];
#pragma unroll
        for (int n = 0; n < 4; ++n)
#pragma unroll
            for (int k2 = 0; k2 < 2; ++k2) {
                const short* kr = &kt[(size_t)(n * 16 + lr) * HH + k2 * 32 + 4 * lg];
                kf[n * 2 + k2][0] = *reinterpret_cast<const s16x4*>(kr);
                kf[n * 2 + k2][1] = *reinterpret_cast<const s16x4*>(kr + 16);
                const short* vr = &vt[(size_t)(n * 16 + lr) * TT + k2 * 32 + 4 * lg];
                vf[n * 2 + k2][0] = *reinterpret_cast<const s16x4*>(vr);
                vf[n * 2 + k2][1] = *reinterpret_cast<const s16x4*>(vr + 16);
            }

        // ---- S = Q K^T : S[row=4lg+j][kv=n*16+lr] ----
        f32x4 s[4] = {};
#pragma unroll
        for (int k2 = 0; k2 < 2; ++k2)
#pragma unroll
            for (int n = 0; n < 4; ++n)
                s[n] = __builtin_amdgcn_mfma_f32_16x16x32_bf16(
                    aQ[k2], cat8(kf[n * 2 + k2][0], kf[n * 2 + k2][1]), s[n], 0, 0, 0);

        // ---- causal mask (only last tile can cross the diagonal) ----
        if (jt == ntiles - 1) {
#pragma unroll
            for (int n = 0; n < 4; ++n)
#pragma unroll
                for (int j = 0; j < 4; ++j)
                    if (jt * 64 + n * 16 + lr > q0 + 4 * lg + j) s[n][j] = -3.0e38f;
        }

        // ---- online softmax in exp2 domain (rows per lg-group; reduce over lr) ----
        float tm[4], mnew[4], alpha[4], psum[4];
#pragma unroll
        for (int j = 0; j < 4; ++j)
            tm[j] = fmaxf(fmaxf(s[0][j], s[1][j]), fmaxf(s[2][j], s[3][j]));
#pragma unroll
        for (int off = 1; off <= 8; off <<= 1)
#pragma unroll
            for (int j = 0; j < 4; ++j)
                tm[j] = fmaxf(tm[j], __shfl_xor(tm[j], off));
#pragma unroll
        for (int j = 0; j < 4; ++j) {
            mnew[j]  = fmaxf(m2[j], tm[j] * SC2);
            alpha[j] = exp2f(m2[j] - mnew[j]); // -inf first tile -> 0
            m2[j]    = mnew[j];
            psum[j]  = 0.f;
        }
#pragma unroll
        for (int n = 0; n < 4; ++n)
#pragma unroll
            for (int j = 0; j < 4; ++j) {
                float p = exp2f(fmaf(s[n][j], SC2, -mnew[j]));
                psum[j] += p;
                pst[4 * lg + j][n * 16 + lr] = f2bf(p);
            }
#pragma unroll
        for (int off = 1; off <= 8; off <<= 1)
#pragma unroll
            for (int j = 0; j < 4; ++j)
                psum[j] += __shfl_xor(psum[j], off);
#pragma unroll
        for (int j = 0; j < 4; ++j)
            l_run[j] = l_run[j] * alpha[j] + psum[j];
#pragma unroll
        for (int n = 0; n < 4; ++n)
#pragma unroll
            for (int j = 0; j < 4; ++j)
                o[n][j] *= alpha[j];

        // ---- PV: O += P V (wave-private LDS round-trip, in-order DS ops) ----
        asm volatile("s_waitcnt lgkmcnt(0)" ::: "memory");
        bf16x8 aP[2];
#pragma unroll
        for (int k2 = 0; k2 < 2; ++k2)
            aP[k2] = cat8(*reinterpret_cast<const s16x4*>(&pst[lr][k2 * 32 + 4 * lg]),
                          *reinterpret_cast<const s16x4*>(&pst[lr][k2 * 32 + 16 + 4 * lg]));
#pragma unroll
        for (int k2 = 0; k2 < 2; ++k2)
#pragma unroll
            for (int n = 0; n < 4; ++n)
                o[n] = __builtin_amdgcn_mfma_f32_16x16x32_bf16(
                    aP[k2], cat8(vf[n * 2 + k2][0], vf[n * 2 + k2][1]), o[n], 0, 0, 0);
    }

    float inv[4];
#pragma unroll
    for (int j = 0; j < 4; ++j) inv[j] = 1.f / l_run[j];
    float* ob = out + ((size_t)b * TT + q0) * HH;
#pragma unroll
    for (int n = 0; n < 4; ++n)
#pragma unroll
        for (int j = 0; j < 4; ++j)
            ob[(size_t)(4 * lg + j) * HH + n * 16 + lr] = o[n][j] * inv[j];
}

extern "C" void kernel_launch(void* const* d_in, const int* in_sizes, int n_in,
                              void* d_out, int out_size, void* d_ws, size_t ws_size,
                              hipStream_t stream) {
    const float* x  = (const float*)d_in[0];
    const float* Wk = (const float*)d_in[1];
    const float* Wq = (const float*)d_in[2];
    const float* Wv = (const float*)d_in[3];
    float* outp = (float*)d_out;

    const size_t n = (size_t)BB * TT * HH; // 1,048,576
    short* kbuf = (short*)d_ws;
    short* qbuf = kbuf + n;
    short* vbuf = qbuf + n;   // vT layout [B][H][T]

    proj_fused<<<256, 256, 0, stream>>>(x, Wk, Wq, Wv, kbuf, qbuf, vbuf);
    attn_reg<<<1024, 64, 0, stream>>>(qbuf, kbuf, vbuf, outp);
}